// Round 1
// baseline (573.085 us; speedup 1.0000x reference)
//
#include <hip/hip_runtime.h>

// ApplyDF: deep-filter first NB_DF complex bins with 5-tap causal complex FIR
// over time; remaining bins pass through.
//
// spec : (B=32, 1, T=2000, F=481, 2) fp32
// coefs: (B=32, ORDER=5, T=2000, NB_DF=96, 2) fp32
// out  : same shape as spec
//
// out[b,t,f<96] = sum_n spec[b, t+n-4, f] * coefs[b,n,t,f]  (complex, zero-pad t<0)
// out[b,t,f>=96] = spec[b,t,f]
//
// v2: sliding-window FIR (thread owns 2 bins, walks TCHUNK=25 t-steps, 5-tap
// window in registers) + flat grid-stride copy role in the same launch.
// Compulsory traffic ~738 MB -> ~117 us at 6.3 TB/s; previous structure was
// instruction-bound at 562 us (1.3 TB/s effective).

constexpr int ORDER = 5;
constexpr int NB_DF = 96;
constexpr int T_DIM = 2000;
constexpr int F_DIM = 481;
constexpr int B_DIM = 32;

constexpr int TCHUNK = 25;                       // t-steps per FIR thread
constexpr int NCHUNK = T_DIM / TCHUNK;           // 80
constexpr int F4     = NB_DF / 2;                // 48 float4 columns (2 bins each)
constexpr int BLOCK  = 256;

constexpr int FIR_THREADS = B_DIM * NCHUNK * F4; // 122880
constexpr int FIR_BLOCKS  = FIR_THREADS / BLOCK; // 480 (exact)

constexpr int COPY_BLOCKS = 3616;                // total grid = 4096 blocks
constexpr int COPY_F      = F_DIM - NB_DF;       // 385 float2 per row
constexpr int N_ROWS      = B_DIM * T_DIM;       // 64000
constexpr unsigned COPY_ELEMS = (unsigned)N_ROWS * (unsigned)COPY_F; // 24,640,000

__global__ __launch_bounds__(BLOCK) void ApplyDF_29231547416739_kernel(
    const float2* __restrict__ spec,
    const float4* __restrict__ coefs4,   // coefs rows are 768 B -> 16B-aligned
    float2* __restrict__ out)
{
    const int bid = blockIdx.x;
    const int tid = threadIdx.x;

    if (bid < FIR_BLOCKS) {
        // ---------------- FIR role ----------------
        const int flat  = bid * BLOCK + tid;      // 0..122879
        const int col   = flat % F4;              // float4 column: bins 2col,2col+1
        const int chunk = flat / F4;              // 0..2559
        const int b     = chunk / NCHUNK;
        const int t0    = (chunk % NCHUNK) * TCHUNK;

        const size_t bT = (size_t)b * T_DIM;

        // spec/out are float2 (rows are 3848 B: float4 would be misaligned on
        // odd rows), coefs are float4.
        const float2* sp = spec + (bT + t0) * F_DIM + col * 2;
        float2*       op = out  + (bT + t0) * F_DIM + col * 2;

        // coefs index: ((b*ORDER + n)*T_DIM + t)*F4 + col  (float4 units)
        const float4* cp[ORDER];
#pragma unroll
        for (int n = 0; n < ORDER; ++n)
            cp[n] = coefs4 + ((bT * ORDER) + (size_t)n * T_DIM + t0) * F4 + col;

        // Sliding window: time tau = t0 + m - 4 lives in slot m%5.
        float4 w[ORDER];
#pragma unroll
        for (int j = 0; j < ORDER - 1; ++j) {     // warm-up: taps t0-4 .. t0-1
            float4 v = make_float4(0.f, 0.f, 0.f, 0.f);
            const int tt = t0 - (ORDER - 1) + j;
            if (tt >= 0) {
                const float2* p = sp + (j - (ORDER - 1)) * F_DIM;
                const float2 lo = p[0], hi = p[1];
                v = make_float4(lo.x, lo.y, hi.x, hi.y);
            }
            w[j] = v;
        }

        // 5 groups of 5 fully-unrolled steps: all %5 indices are compile-time
        // constants (runtime-indexed reg arrays would spill to scratch).
        for (int g = 0; g < TCHUNK / ORDER; ++g) {
#pragma unroll
            for (int r = 0; r < ORDER; ++r) {
                {   // newest tap (time t0+5g+r) -> slot (r+4)%5
                    const float2 lo = sp[0], hi = sp[1];
                    w[(r + ORDER - 1) % ORDER] = make_float4(lo.x, lo.y, hi.x, hi.y);
                }
                float4 acc = make_float4(0.f, 0.f, 0.f, 0.f);
#pragma unroll
                for (int n = 0; n < ORDER; ++n) {
                    const float4 c = *cp[n];
                    const float4 s4 = w[(r + n) % ORDER];
                    acc.x = fmaf(s4.x, c.x, fmaf(-s4.y, c.y, acc.x));
                    acc.y = fmaf(s4.x, c.y, fmaf( s4.y, c.x, acc.y));
                    acc.z = fmaf(s4.z, c.z, fmaf(-s4.w, c.w, acc.z));
                    acc.w = fmaf(s4.z, c.w, fmaf( s4.w, c.z, acc.w));
                }
                op[0] = make_float2(acc.x, acc.y);
                op[1] = make_float2(acc.z, acc.w);
                sp += F_DIM;
                op += F_DIM;
#pragma unroll
                for (int n = 0; n < ORDER; ++n) cp[n] += F4;
            }
        }
    } else {
        // ---------------- pass-through copy role (f in [96,481)) ----------------
        unsigned i = (unsigned)(bid - FIR_BLOCKS) * BLOCK + tid;
        const unsigned stride = (unsigned)COPY_BLOCKS * BLOCK;
        for (; i < COPY_ELEMS; i += stride) {
            const unsigned row = i / COPY_F;              // magic-mul div
            const unsigned ff  = i - row * COPY_F + NB_DF;
            const size_t off = (size_t)row * F_DIM + ff;
            out[off] = spec[off];
        }
    }
}

extern "C" void kernel_launch(void* const* d_in, const int* in_sizes, int n_in,
                              void* d_out, int out_size, void* d_ws, size_t ws_size,
                              hipStream_t stream) {
    const float2* spec   = (const float2*)d_in[0];
    const float4* coefs4 = (const float4*)d_in[1];
    float2* out = (float2*)d_out;

    dim3 grid(FIR_BLOCKS + COPY_BLOCKS);
    dim3 block(BLOCK);
    ApplyDF_29231547416739_kernel<<<grid, block, 0, stream>>>(spec, coefs4, out);
}

// Round 2
// 551.737 us; speedup vs baseline: 1.0387x; 1.0387x over previous
//
#include <hip/hip_runtime.h>

// ApplyDF: deep-filter first NB_DF complex bins with 5-tap causal complex FIR
// over time; remaining bins pass through.
//
// spec : (B=32, 1, T=2000, F=481, 2) fp32
// coefs: (B=32, ORDER=5, T=2000, NB_DF=96, 2) fp32
// out  : same shape as spec
//
// out[b,t,f<96] = sum_n spec[b, t+n-4, f] * coefs[b,n,t,f]  (complex, zero-pad t<0)
// out[b,t,f>=96] = spec[b,t,f]
//
// v3: MLP-first rewrite. v2 measured 210 us at 2.4 TB/s with VALUBusy 5.7%,
// occupancy 70%, VGPR=36 -> latency-bound at ~1 outstanding load per thread.
// This version makes every thread issue a batch of independent loads:
//  - FIR: one thread per (b,t,bin-pair): 5 float4 coef + 10 float2 spec loads,
//    all independent (~160 B in flight per lane), branchless zero-padding.
//  - copy: 4-way batched grid-stride (4 loads, then 4 stores).
//  - roles interleaved by bid&1 so copy traffic overlaps FIR compute.

constexpr int ORDER = 5;
constexpr int NB_DF = 96;
constexpr int T_DIM = 2000;
constexpr int F_DIM = 481;
constexpr int B_DIM = 32;

constexpr int F4    = NB_DF / 2;     // 48 bin-pairs (one float4 coef col each)
constexpr int BLOCK = 256;

constexpr int FIR_THREADS = B_DIM * T_DIM * F4;      // 3,072,000
constexpr int FIR_BLOCKS  = FIR_THREADS / BLOCK;     // 12,000 (exact)

constexpr int COPY_BLOCKS = FIR_BLOCKS;              // 12,000 (interleaved 1:1)
constexpr int COPY_F      = F_DIM - NB_DF;           // 385 float2 per row
constexpr int N_ROWS      = B_DIM * T_DIM;           // 64,000
constexpr unsigned COPY_ELEMS  = (unsigned)N_ROWS * (unsigned)COPY_F;  // 24,640,000
constexpr unsigned COPY_STRIDE = (unsigned)COPY_BLOCKS * BLOCK;        // 3,072,000
// 24,640,000 = 8*3,072,000 + 64,000  -> 8 full iterations + 64,000-elem tail

__global__ __launch_bounds__(BLOCK, 6) void ApplyDF_29231547416739_kernel(
    const float2* __restrict__ spec,
    const float4* __restrict__ coefs4,   // coef rows are 768 B -> 16B-aligned
    float2* __restrict__ out)
{
    const int bid = blockIdx.x;
    const int tid = threadIdx.x;
    const int half = bid >> 1;

    if ((bid & 1) == 0) {
        // ---------------- FIR role: one thread = one (b,t, bin pair) ----------
        const int flat = half * BLOCK + tid;      // 0..3,071,999
        const int col  = flat % F4;               // bins 2col, 2col+1
        const int rest = flat / F4;               // b*T_DIM + t
        const int b    = rest / T_DIM;
        const int t    = rest - b * T_DIM;

        // --- issue ALL loads up front; everything below is independent ---
        // spec taps (zero-pad tt<0 via clamp+select; loads stay unconditional)
        float2 slo[ORDER], shi[ORDER];
#pragma unroll
        for (int n = 0; n < ORDER; ++n) {
            const int tt  = t + n - (ORDER - 1);
            const int ttc = tt >= 0 ? tt : 0;
            const float2* p = spec + ((size_t)b * T_DIM + ttc) * F_DIM + 2 * col;
            float2 lo = p[0];
            float2 hi = p[1];
            if (tt < 0) { lo = make_float2(0.f, 0.f); hi = make_float2(0.f, 0.f); }
            slo[n] = lo; shi[n] = hi;
        }
        // coef taps
        float4 c[ORDER];
#pragma unroll
        for (int n = 0; n < ORDER; ++n)
            c[n] = coefs4[(((size_t)b * ORDER + n) * T_DIM + t) * F4 + col];

        float4 acc = make_float4(0.f, 0.f, 0.f, 0.f);
#pragma unroll
        for (int n = 0; n < ORDER; ++n) {
            acc.x = fmaf(slo[n].x, c[n].x, fmaf(-slo[n].y, c[n].y, acc.x));
            acc.y = fmaf(slo[n].x, c[n].y, fmaf( slo[n].y, c[n].x, acc.y));
            acc.z = fmaf(shi[n].x, c[n].z, fmaf(-shi[n].y, c[n].w, acc.z));
            acc.w = fmaf(shi[n].x, c[n].w, fmaf( shi[n].y, c[n].z, acc.w));
        }

        float2* op = out + ((size_t)b * T_DIM + t) * F_DIM + 2 * col;
        op[0] = make_float2(acc.x, acc.y);
        op[1] = make_float2(acc.z, acc.w);
    } else {
        // ---------------- copy role (f in [96,481)), 4-way batched ------------
        const unsigned base = (unsigned)half * BLOCK + tid;
#pragma unroll
        for (int rep = 0; rep < 2; ++rep) {
            const unsigned i0 = base + (unsigned)(rep * 4) * COPY_STRIDE;
            size_t off[4];
            float2 v[4];
#pragma unroll
            for (int u = 0; u < 4; ++u) {
                const unsigned idx = i0 + (unsigned)u * COPY_STRIDE;
                const unsigned row = idx / COPY_F;            // magic-mul div
                const unsigned ff  = idx - row * COPY_F + NB_DF;
                off[u] = (size_t)row * F_DIM + ff;
                v[u]   = spec[off[u]];
            }
#pragma unroll
            for (int u = 0; u < 4; ++u) out[off[u]] = v[u];
        }
        // tail: 64,000 leftover elements
        if (base < 64000u) {
            const unsigned idx = base + 8u * COPY_STRIDE;
            const unsigned row = idx / COPY_F;
            const unsigned ff  = idx - row * COPY_F + NB_DF;
            const size_t off   = (size_t)row * F_DIM + ff;
            out[off] = spec[off];
        }
    }
}

extern "C" void kernel_launch(void* const* d_in, const int* in_sizes, int n_in,
                              void* d_out, int out_size, void* d_ws, size_t ws_size,
                              hipStream_t stream) {
    const float2* spec   = (const float2*)d_in[0];
    const float4* coefs4 = (const float4*)d_in[1];
    float2* out = (float2*)d_out;

    dim3 grid(FIR_BLOCKS + COPY_BLOCKS);   // 24,000 blocks, roles interleaved
    dim3 block(BLOCK);
    ApplyDF_29231547416739_kernel<<<grid, block, 0, stream>>>(spec, coefs4, out);
}